// Round 12
// baseline (256.397 us; speedup 1.0000x reference)
//
#include <hip/hip_runtime.h>

// MorphoMLP: y = relu(maxplus(relu(maxplus(x,W1)), W2)), fp32.
// B=512, IN=512, HID=1024, OUT=512.
// R14: MEASUREMENT ROUND on the R13 structure (91.2us best). All four
//      pipeline kernels dilated by idempotent repetition so each out-ranks
//      the ~40us harness fills in rocprof top-5:
//        morphos x8 (acc = max over re-staged identical data, bit-identical)
//        combineH x32 / combineY x48 (re-read/re-write same values;
//        __restrict__ removed + runtime rep count so hipcc can't collapse).
//      Steady-state cost = dur/rep. Pins m1, m2, cH, cY, and by subtraction
//      the per-boundary fixed cost. R13 remains the banked best.
// ws: hp 8MB | A2 2MB | yp 8MB = 18MB

#define WS_HP   0                            // [4][512][1024]  L1 partials [z][b][j]
#define WS_A2   (4 * 512 * 1024)             // [512][1024]     relu(h) [b][k2]
#define WS_YP   (WS_A2 + 512 * 1024)         // [8][512][512]   L2 partials [z][b][o]

typedef float f32x2 __attribute__((ext_vector_type(2)));

__device__ __forceinline__ float4 fmax4(float4 a, float4 b) {
    return make_float4(fmaxf(a.x, b.x), fmaxf(a.y, b.y),
                       fmaxf(a.z, b.z), fmaxf(a.w, b.w));
}

// ---------------------------------------------------------------------------
// R13 morphoNT3 + MREP outer repetition (idempotent: max over same data).
template <int JTILE, int KPER, int AROWF4, int WROWF4, int OUTW, int MREP>
__global__ __launch_bounds__(256, 2) void morphoNT3R(const float* __restrict__ A,
                                                     const float* __restrict__ Wm,
                                                     float* __restrict__ P) {
    constexpr int JROWS = JTILE / 16;
    __shared__ float lA[64 * 64];
    __shared__ float lW[JTILE * 64];
    const int t  = threadIdx.x;
    const int tx = t >> 4;
    const int ty = t & 15;
    const int j0 = blockIdx.x * JTILE;
    const int b0 = blockIdx.y * 64;
    const int kbase = blockIdx.z * (KPER / 4);

    const float4* A4 = (const float4*)A;
    const float4* W4 = (const float4*)Wm;
    float4* lA4 = (float4*)lA;
    float4* lW4 = (float4*)lW;

    float acc[4][JROWS];
#pragma unroll
    for (int bi = 0; bi < 4; bi++)
#pragma unroll
        for (int jr = 0; jr < JROWS; jr++) acc[bi][jr] = 0.0f;

    const int swA = tx & 7;
    const int swW = ty & 7;

    for (int rep = 0; rep < MREP; rep++) {
        for (int ph = 0; ph < KPER / 64; ph++) {
            if (ph | rep) __syncthreads();
            const int kf4 = kbase + ph * 16;

#pragma unroll
            for (int s = 0; s < 4; s++) {
                const int q = t + 256 * s;
                const int r = q >> 4, c = q & 15;
                lA4[r * 16 + (c ^ ((r >> 2) & 7))] =
                    A4[(size_t)(b0 + r) * AROWF4 + kf4 + c];
            }
#pragma unroll
            for (int s = 0; s < JTILE / 16; s++) {
                const int q = t + 256 * s;
                const int r = q >> 4, c = q & 15;
                lW4[r * 16 + (c ^ ((r >> 2) & 7))] =
                    W4[(size_t)(j0 + r) * WROWF4 + kf4 + c];
            }
            __syncthreads();

            const float4* pA  = lA4 + tx * 4 * 16;
            const float4* pWl = lW4 + ty * 4 * 16;

#pragma unroll 4
            for (int c = 0; c < 16; c++) {
                const int cA = c ^ swA, cW = c ^ swW;
                float4 a[4];
#pragma unroll
                for (int bi = 0; bi < 4; bi++) a[bi] = pA[bi * 16 + cA];
                float4 w[JROWS];
#pragma unroll
                for (int ji = 0; ji < JROWS; ji++) w[ji] = pWl[ji * 16 + cW];
#pragma unroll
                for (int bi = 0; bi < 4; bi++) {
                    const f32x2 alo = {a[bi].x, a[bi].y};
                    const f32x2 ahi = {a[bi].z, a[bi].w};
#pragma unroll
                    for (int jr = 0; jr < JROWS; jr++) {
                        const f32x2 s = alo + (f32x2){w[jr].x, w[jr].y};
                        const f32x2 u = ahi + (f32x2){w[jr].z, w[jr].w};
                        const float m = fmaxf(fmaxf(s.x, s.y), u.x);
                        acc[bi][jr]   = fmaxf(fmaxf(acc[bi][jr], m), u.y);
                    }
                }
            }
        }
    }

    float* Pp = P + (size_t)blockIdx.z * (512 * OUTW);
#pragma unroll
    for (int bi = 0; bi < 4; bi++) {
        float* row = Pp + (size_t)(b0 + tx * 4 + bi) * OUTW + j0 + ty * 4;
        *(float4*)(row) = make_float4(acc[bi][0], acc[bi][1], acc[bi][2], acc[bi][3]);
    }
}

// ---------------------------------------------------------------------------
// combineH, dilated: no __restrict__ (possible aliasing forces re-execution),
// runtime rep count (no unroll-collapse). Idempotent.
__global__ __launch_bounds__(256) void combineH3R(const float* hp, float* A2,
                                                  int reps) {
    const int i = blockIdx.x * 256 + threadIdx.x;
    const float4* p = (const float4*)hp;
    for (int r = 0; r < reps; r++) {
        float4 m = p[i];
#pragma unroll
        for (int z = 1; z < 4; z++) m = fmax4(m, p[i + z * 131072]);
        m = fmax4(m, make_float4(0.f, 0.f, 0.f, 0.f));
        ((float4*)A2)[i] = m;
    }
}

// ---------------------------------------------------------------------------
// combineY, dilated likewise.
__global__ __launch_bounds__(256) void combineY4R(const float* yp, float* out,
                                                  int reps) {
    const int i = blockIdx.x * 256 + threadIdx.x;
    const float4* p = (const float4*)yp;
    for (int r = 0; r < reps; r++) {
        float4 m = p[i];
#pragma unroll
        for (int z = 1; z < 8; z++) m = fmax4(m, p[i + z * 65536]);
        ((float4*)out)[i] = m;
    }
}

// ---------------------------------------------------------------------------
extern "C" void kernel_launch(void* const* d_in, const int* in_sizes, int n_in,
                              void* d_out, int out_size, void* d_ws, size_t ws_size,
                              hipStream_t stream) {
    (void)in_sizes; (void)n_in; (void)out_size; (void)ws_size;
    const float* x  = (const float*)d_in[0];   // [512][512]   b x k
    const float* W1 = (const float*)d_in[1];   // [1024][512]  j x k
    const float* W2 = (const float*)d_in[2];   // [512][1024]  o x k2
    float* ws  = (float*)d_ws;
    float* out = (float*)d_out;

    // 1) L1 (x8): hp[4][b][j]; grid 16(j) x 8(b) x 4(z), 512 blocks.
    morphoNT3R<64, 128, 128, 128, 1024, 8>
        <<<dim3(16, 8, 4), 256, 0, stream>>>(x, W1, ws + WS_HP);

    // 2) combineH (x32): 4 slices + relu -> A2[b][k2]
    combineH3R<<<512, 256, 0, stream>>>(ws + WS_HP, ws + WS_A2, 32);

    // 3) L2 (x8): yp[8][b][o]; grid 8(o) x 8(b) x 8(z), 512 blocks.
    morphoNT3R<64, 128, 256, 256, 512, 8>
        <<<dim3(8, 8, 8), 256, 0, stream>>>(ws + WS_A2, W2, ws + WS_YP);

    // 4) combineY (x48): 8 slices -> out[b][o]
    combineY4R<<<256, 256, 0, stream>>>(ws + WS_YP, out, 48);
}

// Round 13
// 117.974 us; speedup vs baseline: 2.1733x; 2.1733x over previous
//
#include <hip/hip_runtime.h>

// MorphoMLP: y = relu(maxplus(relu(maxplus(x,W1)), W2)), fp32.
// B=512, IN=512, HID=1024, OUT=512.
// R15: R13 structure (91.2us best; boundary-minimal 39MB) + two cold-path
//      mechanisms, zero structural change:
//   - NONTEMPORAL stores for hp/yp/A2/out + nt loads in combines: partials
//     are write-once/read-once-next-dispatch; nt bypasses L2 -> smaller
//     boundary writeback+invalidate (the fitted 0.11us/MB cost).
//   - DOUBLE-BUFFERED staging in the morphos (T14 async-split): phase-1
//     global loads issued into regs BEFORE phase-0 compute; L3/HBM latency
//     hides under compute. Same 2 barriers; LDS 32->64KB (2 blk/CU ok).
//   - R14 calibration: warm morpho ~12us, cold-extra ~10us each, gaps ~1us,
//     combines ~1us. Fill 40.5us is harness-owned.
// ws: hp 8MB | A2 2MB | yp 8MB = 18MB

#define WS_HP   0                            // [4][512][1024]  L1 partials [z][b][j]
#define WS_A2   (4 * 512 * 1024)             // [512][1024]     relu(h) [b][k2]
#define WS_YP   (WS_A2 + 512 * 1024)         // [8][512][512]   L2 partials [z][b][o]

typedef float f32x2 __attribute__((ext_vector_type(2)));
typedef float f32x4 __attribute__((ext_vector_type(4)));

__device__ __forceinline__ f32x4 fmax4v(f32x4 a, f32x4 b) {
    f32x4 r;
    r.x = fmaxf(a.x, b.x); r.y = fmaxf(a.y, b.y);
    r.z = fmaxf(a.z, b.z); r.w = fmaxf(a.w, b.w);
    return r;
}

// ---------------------------------------------------------------------------
// NT max-plus tile kernel, double-buffered staging + nt partial stores.
// A: [*][AROWF4*4] row-major (b rows); W: [*][WROWF4*4] row-major (j rows).
// Block tile: 64 j x 64 b x 128 k (2 phases of 64k, double-buffered).
// 256 thr: tx=t>>4 -> 4 b-rows; ty=t&15 -> 4 j-rows.
// LDS [row][16 f4], swizzle col^=(row>>2)&7 both sides (R13-verbatim).
// Stores partial P[bz][b][j] (f4 over j) with nontemporal hint.
template <int JTILE, int AROWF4, int WROWF4, int OUTW>
__global__ __launch_bounds__(256, 2) void morphoNT4(const float* __restrict__ A,
                                                    const float* __restrict__ Wm,
                                                    float* __restrict__ P) {
    constexpr int JROWS = JTILE / 16;          // 4
    __shared__ float lA[2][64 * 64];           // [buf][b-row][64k] 16KB each
    __shared__ float lW[2][JTILE * 64];        // [buf][j-row][64k] 16KB each
    const int t  = threadIdx.x;
    const int tx = t >> 4;
    const int ty = t & 15;
    const int j0 = blockIdx.x * JTILE;
    const int b0 = blockIdx.y * 64;
    const int kbase = blockIdx.z * 32;         // KPER=128 -> 32 f4 per row

    const float4* A4 = (const float4*)A;
    const float4* W4 = (const float4*)Wm;

    float acc[4][JROWS];
#pragma unroll
    for (int bi = 0; bi < 4; bi++)
#pragma unroll
        for (int jr = 0; jr < JROWS; jr++) acc[bi][jr] = 0.0f;

    const int swA = tx & 7;
    const int swW = ty & 7;

    // ---- staging coordinates: q = t + 256s, r = q>>4, c = q&15 ----
    float4 av[4], wv[4];

    // load phase 0
#pragma unroll
    for (int s = 0; s < 4; s++) {
        const int q = t + 256 * s, r = q >> 4, c = q & 15;
        av[s] = A4[(size_t)(b0 + r) * AROWF4 + kbase + c];
        wv[s] = W4[(size_t)(j0 + r) * WROWF4 + kbase + c];
    }
    // write buf0
#pragma unroll
    for (int s = 0; s < 4; s++) {
        const int q = t + 256 * s, r = q >> 4, c = q & 15;
        ((float4*)lA[0])[r * 16 + (c ^ ((r >> 2) & 7))] = av[s];
        ((float4*)lW[0])[r * 16 + (c ^ ((r >> 2) & 7))] = wv[s];
    }
    // issue phase-1 loads (latency hides under phase-0 compute)
#pragma unroll
    for (int s = 0; s < 4; s++) {
        const int q = t + 256 * s, r = q >> 4, c = q & 15;
        av[s] = A4[(size_t)(b0 + r) * AROWF4 + kbase + 16 + c];
        wv[s] = W4[(size_t)(j0 + r) * WROWF4 + kbase + 16 + c];
    }
    __syncthreads();

#pragma unroll
    for (int ph = 0; ph < 2; ph++) {
        const float4* pA  = ((const float4*)lA[ph]) + tx * 4 * 16;
        const float4* pWl = ((const float4*)lW[ph]) + ty * 4 * 16;

        // ---- k burst: 16 iters x 4k; pk_add + v_max3 (R13-verbatim) ----
#pragma unroll 4
        for (int c = 0; c < 16; c++) {
            const int cA = c ^ swA, cW = c ^ swW;
            float4 a[4];
#pragma unroll
            for (int bi = 0; bi < 4; bi++) a[bi] = pA[bi * 16 + cA];
            float4 w[JROWS];
#pragma unroll
            for (int ji = 0; ji < JROWS; ji++) w[ji] = pWl[ji * 16 + cW];
#pragma unroll
            for (int bi = 0; bi < 4; bi++) {
                const f32x2 alo = {a[bi].x, a[bi].y};
                const f32x2 ahi = {a[bi].z, a[bi].w};
#pragma unroll
                for (int jr = 0; jr < JROWS; jr++) {
                    const f32x2 s = alo + (f32x2){w[jr].x, w[jr].y};  // pk_add
                    const f32x2 u = ahi + (f32x2){w[jr].z, w[jr].w};  // pk_add
                    const float m = fmaxf(fmaxf(s.x, s.y), u.x);      // v_max3
                    acc[bi][jr]   = fmaxf(fmaxf(acc[bi][jr], m), u.y);// v_max3
                }
            }
        }

        if (ph == 0) {
            // write buf1 from regs (disjoint from buf0 readers; no pre-sync)
#pragma unroll
            for (int s = 0; s < 4; s++) {
                const int q = t + 256 * s, r = q >> 4, c = q & 15;
                ((float4*)lA[1])[r * 16 + (c ^ ((r >> 2) & 7))] = av[s];
                ((float4*)lW[1])[r * 16 + (c ^ ((r >> 2) & 7))] = wv[s];
            }
            __syncthreads();
        }
    }

    // ---- store partial: P[bz][b][j], nontemporal (write-once) ----
    float* Pp = P + (size_t)blockIdx.z * (512 * OUTW);
#pragma unroll
    for (int bi = 0; bi < 4; bi++) {
        float* row = Pp + (size_t)(b0 + tx * 4 + bi) * OUTW + j0 + ty * 4;
        f32x4 v = {acc[bi][0], acc[bi][1], acc[bi][2], acc[bi][3]};
        __builtin_nontemporal_store(v, (f32x4*)row);
    }
}

// ---------------------------------------------------------------------------
// combineH: A2[b][k2] = relu(max_z hp[z][b][k2]). nt loads (read-once),
// nt store. 512 blocks x 256 thr x 1 f4.
__global__ __launch_bounds__(256) void combineH4(const float* __restrict__ hp,
                                                 float* __restrict__ A2) {
    const int i = blockIdx.x * 256 + threadIdx.x;
    const f32x4* p = (const f32x4*)hp;
    f32x4 m = __builtin_nontemporal_load(p + i);
#pragma unroll
    for (int z = 1; z < 4; z++)
        m = fmax4v(m, __builtin_nontemporal_load(p + i + z * 131072));
    const f32x4 zero = {0.f, 0.f, 0.f, 0.f};
    m = fmax4v(m, zero);
    __builtin_nontemporal_store(m, (f32x4*)A2 + i);
}

// ---------------------------------------------------------------------------
// combineY: out[b][o] = max_z yp[z][b][o] (pre-relu'd). nt loads, nt store.
// 256 blocks x 256 thr x 1 f4.
__global__ __launch_bounds__(256) void combineY5(const float* __restrict__ yp,
                                                 float* __restrict__ out) {
    const int i = blockIdx.x * 256 + threadIdx.x;
    const f32x4* p = (const f32x4*)yp;
    f32x4 m = __builtin_nontemporal_load(p + i);
#pragma unroll
    for (int z = 1; z < 8; z++)
        m = fmax4v(m, __builtin_nontemporal_load(p + i + z * 65536));
    __builtin_nontemporal_store(m, (f32x4*)out + i);
}

// ---------------------------------------------------------------------------
extern "C" void kernel_launch(void* const* d_in, const int* in_sizes, int n_in,
                              void* d_out, int out_size, void* d_ws, size_t ws_size,
                              hipStream_t stream) {
    (void)in_sizes; (void)n_in; (void)out_size; (void)ws_size;
    const float* x  = (const float*)d_in[0];   // [512][512]   b x k
    const float* W1 = (const float*)d_in[1];   // [1024][512]  j x k
    const float* W2 = (const float*)d_in[2];   // [512][1024]  o x k2
    float* ws  = (float*)d_ws;
    float* out = (float*)d_out;

    // 1) L1: hp[4][b][j]; JTILE=64, K=512 (z=4 x KPER=128, dbuf 2-phase).
    //    grid 16(j) x 8(b) x 4(z) = 512 blocks, 64KB LDS, 2 blk/CU.
    morphoNT4<64, 128, 128, 1024>
        <<<dim3(16, 8, 4), 256, 0, stream>>>(x, W1, ws + WS_HP);

    // 2) combine 4 slices + relu -> A2[b][k2] (2MB)
    combineH4<<<512, 256, 0, stream>>>(ws + WS_HP, ws + WS_A2);

    // 3) L2: yp[8][b][o]; JTILE=64, K=1024 (z=8 x KPER=128, dbuf 2-phase).
    //    grid 8(o) x 8(b) x 8(z) = 512 blocks, 64KB LDS, 2 blk/CU.
    morphoNT4<64, 256, 256, 512>
        <<<dim3(8, 8, 8), 256, 0, stream>>>(ws + WS_A2, W2, ws + WS_YP);

    // 4) combine 8 slices -> out[b][o]
    combineY5<<<256, 256, 0, stream>>>(ws + WS_YP, out);
}